// Round 12
// baseline (270.525 us; speedup 1.0000x reference)
//
#include <hip/hip_runtime.h>
#include <hip/hip_cooperative_groups.h>

namespace cg = cooperative_groups;

#define NB 16
#define NT 50
#define NA 5
#define NH 152
#define NW 152
#define CH 70             // NA*(7+NC)
#define HW (NH*NW)        // 23104
#define AHW (NA*HW)       // 115520
#define NCELL (NB*AHW)    // 1,848,320
#define NWORDS (NCELL/32) // 57,760
#define NTGT (NB*NT)      // 800
#define NSUMB_FB 452      // fallback sum blocks

// ws float layout (313 KB, within proven available footprint)
#define D_XLO 0
#define D_XHI 800
#define D_YLO 1600
#define D_YHI 2400
#define D_GW  3200
#define D_GL  4000
#define D_Q   4800
#define D_TW  5600
#define D_TL  6400
#define D_TIM 7200
#define D_TRE 8000
#define D_GX  8800
#define D_GY  9600
#define D_META 10400      // 800 ints
#define S_SUB 11200       // 801
#define S_CNT 12016       // 801
#define S_WIN 12832       // 801 x 8 -> ends 19240
#define S_SUM 19264       // up to 1280 sum partials
#define M_WORD 20544      // 57,760 u32 words -> ends 78,304 floats

// meta bits: gi[0:8) gj[8:16) bn[16:19) am[19:24) valid[24] validp[25] lab[26:29)

__device__ __forceinline__ float sp_f(float v) {
    return (v > 20.f) ? v : __logf(1.f + __expf(v));
}

__device__ __forceinline__ void prep_one(int id, const float* __restrict__ tgt,
                                         const float* __restrict__ anchors,
                                         float* __restrict__ ws) {
    int b = id / NT, t = id - b * NT;
    const float* tp = tgt + id * 7;
    float lab = tp[0], cx = tp[1], cy = tp[2], w = tp[3], l = tp[4];
    float tim = tp[5], tre = tp[6];
    float sum = lab + cx + cy + w + l + tim + tre;
    bool valid = (sum != 0.0f);
    bool validp = true;
    const float* tb = tgt + (size_t)b * NT * 7;
    for (int t2 = 0; t2 <= t; ++t2) validp = validp && (tb[t2 * 7 + 1] != 0.0f);

    float gx = cx * NW, gy = cy * NH, gw = w * NW, gl = l * NH;
    int gi = min(max((int)gx, 0), NW - 1);
    int gj = min(max((int)gy, 0), NH - 1);

    float agt = (gw + 1.f) * (gl + 1.f);
    float best = -1.f; int bn = 0, am = 0;
    float aw_b = 1.f, ah_b = 1.f;
    for (int a = 0; a < NA; ++a) {
        float aw = anchors[2 * a], ah = anchors[2 * a + 1];
        float iw = fmaxf(fminf(gw, aw) + 1.f, 0.f);
        float ih = fmaxf(fminf(gl, ah) + 1.f, 0.f);
        float inter = iw * ih;
        float aan = (aw + 1.f) * (ah + 1.f);
        float iou = inter / (agt + aan - inter + 1e-16f);
        if (iou > best) { best = iou; bn = a; aw_b = aw; ah_b = ah; }
        if (iou > 0.6f) am |= (1 << a);
    }

    ws[D_XLO + id] = gx - 0.5f * gw;
    ws[D_XHI + id] = gx + 0.5f * gw;
    ws[D_YLO + id] = gy - 0.5f * gl;
    ws[D_YHI + id] = gy + 0.5f * gl;
    ws[D_GW + id]  = gw;
    ws[D_GL + id]  = gl;
    ws[D_Q + id]   = 0.375f * gw * gl;
    ws[D_TW + id]  = logf(gw / aw_b + 1e-16f);
    ws[D_TL + id]  = logf(gl / ah_b + 1e-16f);
    ws[D_TIM + id] = tim;
    ws[D_TRE + id] = tre;
    ws[D_GX + id]  = gx;
    ws[D_GY + id]  = gy;

    int meta = 0;
    if (valid || validp) {
        meta = gi | (gj << 8) | (bn << 16) | (am << 19)
             | (valid ? (1 << 24) : 0) | (validp ? (1 << 25) : 0)
             | ((((int)lab) & 7) << 26);
    }
    ((int*)ws)[D_META + id] = meta;
}

// o[0..6]=loss terms, o[7]=count; lab via select (no scratch)
__device__ __forceinline__ void win_terms(const float* __restrict__ xp,
                                          float tx, float ty, float twv, float tlv,
                                          float timv, float trev, int lab,
                                          float* __restrict__ o) {
    float l[14];
    #pragma unroll
    for (int c = 0; c < 14; ++c) l[c] = xp[c * HW];
    float px = 1.f / (1.f + __expf(-l[0]));
    float py = 1.f / (1.f + __expf(-l[1]));
    o[0] = (px - tx) * (px - tx);
    o[1] = (py - ty) * (py - ty);
    float dw = l[2] - twv; o[2] = dw * dw;
    float dh = l[3] - tlv; o[3] = dh * dh;
    float di = l[4] - timv, dr = l[5] - trev;
    o[4] = di * di + dr * dr;
    o[5] = sp_f(-l[6]);
    float mx = l[7];
    #pragma unroll
    for (int c = 8; c < 14; ++c) mx = fmaxf(mx, l[c]);
    float e[7], se = 0.f;
    #pragma unroll
    for (int c = 0; c < 7; ++c) { e[c] = __expf(l[7 + c] - mx); se += e[c]; }
    float se2 = 0.f, slab = 0.f;
    #pragma unroll
    for (int c = 0; c < 7; ++c) {
        float s = e[c] / se;
        se2 += __expf(s);
        if (c == lab) slab = s;
    }
    o[6] = __logf(se2) - slab;
    o[7] = 1.f;
}

// ---- role bodies (shared between cooperative kernel and fallback path) ----

__device__ __forceinline__ void role_scatter(const float* __restrict__ x,
                                             const float* __restrict__ anchors,
                                             float* __restrict__ ws,
                                             int id, int tid,
                                             float* redA, float* redB, int* s_flag) {
    const int* meta = (const int*)ws + D_META;
    unsigned int* mask = (unsigned int*)ws + M_WORD;
    int b = id / NT, t = id - b * NT;
    int mt = meta[id];

    if (tid == 0) *s_flag = 0;
    __syncthreads();
    if (mt & (1 << 24)) {
        int t2 = t + 1 + tid;
        if (t2 < NT) {
            int m2 = meta[b * NT + t2];
            if ((m2 & (1 << 24)) && ((m2 & 0x7FFFF) == (mt & 0x7FFFF))) *s_flag = 1;
        }
    }
    __syncthreads();

    float sub = 0.f, cnt = 0.f;
    if (tid == 0) {
        float slot[8] = {0.f, 0.f, 0.f, 0.f, 0.f, 0.f, 0.f, 0.f};
        if ((mt & (1 << 24)) && !*s_flag) {   // last-t-wins (np scatter order)
            int gi = mt & 255, gj = (mt >> 8) & 255;
            int bn = (mt >> 16) & 7, lab = (mt >> 26) & 7;
            const float* xp = x + (size_t)(b * CH + bn * 14) * HW + gj * NW + gi;
            win_terms(xp, ws[D_GX + id] - (float)gi, ws[D_GY + id] - (float)gj,
                      ws[D_TW + id], ws[D_TL + id],
                      ws[D_TIM + id], ws[D_TRE + id], lab, slot);
        }
        float* dst = ws + S_WIN + id * 8;
        #pragma unroll
        for (int k = 0; k < 8; ++k) dst[k] = slot[k];
        // override cells: subtract on first-set
        if (mt & (1 << 24)) {
            int gi = mt & 255, gj = (mt >> 8) & 255;
            int bn = (mt >> 16) & 7, am = (mt >> 19) & 31;
            for (int a = 0; a < NA; ++a) {
                if (((am >> a) & 1) || a == bn) {
                    int c = ((b * NA + a) * NH + gj) * NW + gi;
                    unsigned int old = atomicOr(&mask[c >> 5], 1u << (c & 31));
                    if (!((old >> (c & 31)) & 1u)) {
                        cnt += 1.f;
                        sub += sp_f(x[(size_t)(b * CH + a * 14 + 6) * HW + gj * NW + gi]);
                    }
                }
            }
        }
    }
    if (mt & (1 << 25)) {
        float gxv = ws[D_GX + id], gyv = ws[D_GY + id];
        float tgw = ws[D_GW + id], tgl = ws[D_GL + id];
        float txlo = ws[D_XLO + id], txhi = ws[D_XHI + id];
        float tylo = ws[D_YLO + id], tyhi = ws[D_YHI + id];
        float tq = ws[D_Q + id];
        if (tgw > 0.f && tgl > 0.f) {
            // proven reach: pass => |bx-gx| < gw/3, |by-gy| < gl/3 (+1 margin)
            float gw3 = tgw * (1.f / 3.f), gl3 = tgl * (1.f / 3.f);
            int i_lo = max(0, (int)floorf(gxv - gw3) - 1);
            int i_hi = min(NW - 1, (int)floorf(gxv + gw3) + 1);
            int j_lo = max(0, (int)floorf(gyv - gl3) - 1);
            int j_hi = min(NH - 1, (int)floorf(gyv + gl3) + 1);
            int W = i_hi - i_lo + 1, Hh = j_hi - j_lo + 1;
            int total = W * Hh * NA;
            for (int idx = tid; idx < total; idx += 256) {
                int dx = idx % W;
                int q2 = idx / W;
                int j = j_lo + q2 % Hh;
                int a = q2 / Hh;
                int i = i_lo + dx;
                const float* xp = x + (size_t)(b * CH + a * 14) * HW + j * NW + i;
                float l0 = xp[0], l1 = xp[HW], l2 = xp[2 * HW], l3 = xp[3 * HW];
                float aw = anchors[2 * a], ah = anchors[2 * a + 1];
                float bxv = (float)i + 1.f / (1.f + __expf(-l0));
                float byv = (float)j + 1.f / (1.f + __expf(-l1));
                float bw = __expf(l2) * aw;
                float bh = __expf(l3) * ah;
                float mxv = fminf(bxv - 0.5f * bw, txlo);
                float Mxv = fmaxf(bxv + 0.5f * bw, txhi);
                float myv = fminf(byv - 0.5f * bh, tylo);
                float Myv = fmaxf(byv + 0.5f * bh, tyhi);
                float cw = bw + tgw - (Mxv - mxv);
                float chh = bh + tgl - (Myv - myv);
                // iou > 0.6  <=>  carea > 0.375*(area_b + area_g)
                if (cw > 0.f && chh > 0.f && cw * chh > 0.375f * bw * bh + tq) {
                    int c = ((b * NA + a) * NH + j) * NW + i;
                    unsigned int old = atomicOr(&mask[c >> 5], 1u << (c & 31));
                    if (!((old >> (c & 31)) & 1u)) {
                        cnt += 1.f;
                        sub += sp_f(xp[6 * HW]);
                    }
                }
            }
        }
    }
    redA[tid] = sub; redB[tid] = cnt;
    __syncthreads();
    for (int s = 128; s > 0; s >>= 1) {
        if (tid < s) { redA[tid] += redA[tid + s]; redB[tid] += redB[tid + s]; }
        __syncthreads();
    }
    if (tid == 0) { ws[S_SUB + id] = redA[0]; ws[S_CNT + id] = redB[0]; }
}

__device__ __forceinline__ void role_cstar(const float* __restrict__ x,
                                           const float* __restrict__ tgt,
                                           float* __restrict__ ws,
                                           int tid, int* s_flag) {
    if (tid == 0) *s_flag = 0;
    __syncthreads();
    for (int id = tid; id < NTGT; id += 256) {
        const float* tp = tgt + (size_t)id * 7;
        float s7 = tp[0] + tp[1] + tp[2] + tp[3] + tp[4] + tp[5] + tp[6];
        if (s7 == 0.f) *s_flag = 1;   // wrap exists (benign monotone race)
    }
    __syncthreads();
    if (tid == 0) {
        unsigned int* mask = (unsigned int*)ws + M_WORD;
        float slot[8] = {0.f, 0.f, 0.f, 0.f, 0.f, 0.f, 0.f, 0.f};
        float sub = 0.f, cnt = 0.f;
        if (*s_flag) {
            // np negative-index wrap cell c*: last invalid row's values
            const float* xp = x + (size_t)((NB - 1) * CH + (NA - 1) * 14) * HW + (HW - 1);
            float L16 = logf(1e-16f);
            win_terms(xp, 0.f, 0.f, L16, L16, 0.f, 0.f, 0, slot);
            int c = NCELL - 1;
            unsigned int old = atomicOr(&mask[c >> 5], 1u << (c & 31));
            if (!((old >> (c & 31)) & 1u)) {
                cnt = 1.f;
                sub = sp_f(xp[6 * HW]);
            }
        }
        float* dst = ws + S_WIN + NTGT * 8;
        #pragma unroll
        for (int k = 0; k < 8; ++k) dst[k] = slot[k];
        ws[S_SUB + NTGT] = sub;
        ws[S_CNT + NTGT] = cnt;
    }
}

__device__ __forceinline__ void role_sum(const float* __restrict__ x,
                                         float* __restrict__ ws,
                                         int rb, int S, int tid, float* redA) {
    float s = 0.f;
    int stride = S * 256 * 4;
    for (int c4 = (rb * 256 + tid) * 4; c4 < NCELL; c4 += stride) {
        int b = c4 / AHW;
        int within = c4 - b * AHW;
        int a = within / HW;
        int rem = within - a * HW;
        const float* p = x + (size_t)(b * CH + a * 14 + 6) * HW + rem;
        float4 v = *(const float4*)p;
        s += sp_f(v.x) + sp_f(v.y) + sp_f(v.z) + sp_f(v.w);
    }
    redA[tid] = s;
    __syncthreads();
    for (int st = 128; st > 0; st >>= 1) {
        if (tid < st) redA[tid] += redA[tid + st];
        __syncthreads();
    }
    if (tid == 0) ws[S_SUM + rb] = redA[0];
}

__device__ __forceinline__ void do_reduce(const float* __restrict__ ws,
                                          float* __restrict__ out,
                                          int S, int tid, double sw[4][11]) {
    double acc[11];
    #pragma unroll
    for (int k = 0; k < 11; ++k) acc[k] = 0.0;
    for (int s2 = tid; s2 < NTGT + 1; s2 += 256) {
        const float* p = ws + S_WIN + s2 * 8;
        #pragma unroll
        for (int k = 0; k < 8; ++k) acc[k] += (double)p[k];
        acc[8] += (double)ws[S_SUB + s2];
        acc[9] += (double)ws[S_CNT + s2];
    }
    for (int s2 = tid; s2 < S; s2 += 256) acc[10] += (double)ws[S_SUM + s2];

    #pragma unroll
    for (int off = 32; off > 0; off >>= 1)
        #pragma unroll
        for (int k = 0; k < 11; ++k) acc[k] += __shfl_down(acc[k], off);
    int wv = tid >> 6, ln = tid & 63;
    if (ln == 0)
        #pragma unroll
        for (int k = 0; k < 11; ++k) sw[wv][k] = acc[k];
    __syncthreads();
    if (tid == 0) {
        double R[11];
        #pragma unroll
        for (int k = 0; k < 11; ++k) R[k] = sw[0][k] + sw[1][k] + sw[2][k] + sw[3][k];
        double nM  = fmax(R[7], 1.0);
        double scf = fmax((double)NCELL - R[9], 1.0);
        double bce = R[10] - R[8];
        double loss = (R[0] + R[1] + R[2] + R[3] + R[4] + R[5]) / nM
                    + bce / scf
                    + (1.0 / NB) * R[6] / nM;
        out[0] = (float)loss;
    }
}

// ---------------- cooperative single-kernel path ----------------
__global__ void __launch_bounds__(256, 6) k_all(const float* __restrict__ x,
                                                const float* __restrict__ tgt,
                                                const float* __restrict__ anc,
                                                float* __restrict__ ws,
                                                float* __restrict__ out,
                                                int S) {
    __shared__ float redA[256], redB[256];
    __shared__ int s_flag;
    __shared__ double sw[4][11];
    cg::grid_group grid = cg::this_grid();
    int tid = threadIdx.x, bx = blockIdx.x;
    int G = gridDim.x;

    // phase 0: zero mask + prep descriptors
    int gtid = bx * 256 + tid;
    for (int wdx = gtid; wdx < NWORDS; wdx += G * 256)
        ((unsigned int*)ws)[M_WORD + wdx] = 0u;
    if (gtid < NTGT) prep_one(gtid, tgt, anc, ws);
    grid.sync();

    // phase 1: roles
    if (bx < NTGT)       role_scatter(x, anc, ws, bx, tid, redA, redB, &s_flag);
    else if (bx == NTGT) role_cstar(x, tgt, ws, tid, &s_flag);
    else                 role_sum(x, ws, bx - (NTGT + 1), S, tid, redA);
    grid.sync();

    // phase 2: block 0 reduces + assembles
    if (bx == 0) do_reduce(ws, out, S, tid, sw);
}

// ---------------- fallback 3-kernel path (round-11 proven) ----------------
__global__ void __launch_bounds__(256) k_prep_zero(const float* __restrict__ tgt,
                                                   const float* __restrict__ anc,
                                                   float* __restrict__ ws) {
    int gtid = blockIdx.x * 256 + threadIdx.x;
    if (gtid < NWORDS) ((unsigned int*)ws)[M_WORD + gtid] = 0u;
    if (gtid < NTGT) prep_one(gtid, tgt, anc, ws);
}

__global__ void __launch_bounds__(256) k_work(const float* __restrict__ x,
                                              const float* __restrict__ tgt,
                                              const float* __restrict__ anc,
                                              float* __restrict__ ws) {
    __shared__ float redA[256], redB[256];
    __shared__ int s_flag;
    int tid = threadIdx.x, bx = blockIdx.x;
    if (bx < NTGT)       role_scatter(x, anc, ws, bx, tid, redA, redB, &s_flag);
    else if (bx == NTGT) role_cstar(x, tgt, ws, tid, &s_flag);
    else                 role_sum(x, ws, bx - (NTGT + 1), NSUMB_FB, tid, redA);
}

__global__ void __launch_bounds__(256) k_reduce(const float* __restrict__ ws,
                                                float* __restrict__ out, int S) {
    __shared__ double sw[4][11];
    do_reduce(ws, out, S, threadIdx.x, sw);
}

extern "C" void kernel_launch(void* const* d_in, const int* in_sizes, int n_in,
                              void* d_out, int out_size, void* d_ws, size_t ws_size,
                              hipStream_t stream) {
    const float* x   = (const float*)d_in[0];
    const float* tgt = (const float*)d_in[1];
    const float* anc = (const float*)d_in[2];
    float* ws  = (float*)d_ws;
    float* out = (float*)d_out;

    // try single cooperative kernel (saves 2 launches + gaps)
    int occ = 0, ncu = 0, dev = 0;
    hipError_t e1 = hipOccupancyMaxActiveBlocksPerMultiprocessor(&occ, k_all, 256, 0);
    hipGetDevice(&dev);
    hipDeviceGetAttribute(&ncu, hipDeviceAttributeMultiprocessorCount, dev);
    long gmax = (long)occ * (long)ncu;
    if (e1 == hipSuccess && ncu > 0 && gmax >= NTGT + 1 + 64) {
        int G = (int)(gmax < 2048 ? gmax : 2048);
        int S = G - (NTGT + 1);
        void* args[6] = {(void*)&x, (void*)&tgt, (void*)&anc,
                         (void*)&ws, (void*)&out, (void*)&S};
        hipError_t le = hipLaunchCooperativeKernel(reinterpret_cast<void*>(k_all),
                                                   dim3(G), dim3(256), args, 0, stream);
        if (le == hipSuccess) return;
    }

    // fallback: proven round-11 structure
    hipLaunchKernelGGL(k_prep_zero, dim3((NWORDS + 255) / 256), dim3(256), 0, stream,
                       tgt, anc, ws);
    hipLaunchKernelGGL(k_work, dim3(NTGT + 1 + NSUMB_FB), dim3(256), 0, stream,
                       x, tgt, anc, ws);
    hipLaunchKernelGGL(k_reduce, dim3(1), dim3(256), 0, stream, ws, out, NSUMB_FB);
}

// Round 13
// 29.940 us; speedup vs baseline: 9.0355x; 9.0355x over previous
//
#include <hip/hip_runtime.h>

#define NB 16
#define NT 50
#define NA 5
#define NH 152
#define NW 152
#define CH 70             // NA*(7+NC)
#define HW (NH*NW)        // 23104
#define AHW (NA*HW)       // 115520
#define NCELL (NB*AHW)    // 1,848,320
#define NWORDS (NCELL/32) // 57,760
#define NTGT (NB*NT)      // 800

#define NSUMB 452
#define SUM_IT 4          // 452*256*4*4 >= NCELL (bounds-checked)
#define GRID2 (NTGT + NTGT + 1 + NSUMB)   // 800 scatter + 801 winner + 452 sum

// ws float layout (within round-5's proven 326 KB footprint)
#define D_XLO 0
#define D_XHI 800
#define D_YLO 1600
#define D_YHI 2400
#define D_GW  3200
#define D_GL  4000
#define D_Q   4800
#define D_TW  5600
#define D_TL  6400
#define D_TIM 7200
#define D_TRE 8000
#define D_GX  8800
#define D_GY  9600
#define D_META 10400      // 800 ints
#define S_SUM 11200       // 452 grand-sum partials
#define S_SUB 11712       // 801 first-setter subtract partials
#define S_CNT 12520       // 801 first-setter counts
#define M_WORD 16384      // u32 mask bits [16384,74144)
#define S_WIN 74144       // 801 x 8 winner slots -> ends 80552 (322 KB)

// meta bits: gi[0:8) gj[8:16) bn[16:19) am[19:24) valid[24] validp[25] lab[26:29)

__device__ __forceinline__ float sp_f(float v) {
    return (v > 20.f) ? v : __logf(1.f + __expf(v));
}

__device__ __forceinline__ void prep_one(int id, const float* __restrict__ tgt,
                                         const float* __restrict__ anchors,
                                         float* __restrict__ ws) {
    int b = id / NT, t = id - b * NT;
    const float* tp = tgt + id * 7;
    float lab = tp[0], cx = tp[1], cy = tp[2], w = tp[3], l = tp[4];
    float tim = tp[5], tre = tp[6];
    float sum = lab + cx + cy + w + l + tim + tre;
    bool valid = (sum != 0.0f);
    bool validp = true;
    const float* tb = tgt + (size_t)b * NT * 7;
    for (int t2 = 0; t2 <= t; ++t2) validp = validp && (tb[t2 * 7 + 1] != 0.0f);

    float gx = cx * NW, gy = cy * NH, gw = w * NW, gl = l * NH;
    int gi = min(max((int)gx, 0), NW - 1);
    int gj = min(max((int)gy, 0), NH - 1);

    float agt = (gw + 1.f) * (gl + 1.f);
    float best = -1.f; int bn = 0, am = 0;
    float aw_b = 1.f, ah_b = 1.f;
    for (int a = 0; a < NA; ++a) {
        float aw = anchors[2 * a], ah = anchors[2 * a + 1];
        float iw = fmaxf(fminf(gw, aw) + 1.f, 0.f);
        float ih = fmaxf(fminf(gl, ah) + 1.f, 0.f);
        float inter = iw * ih;
        float aan = (aw + 1.f) * (ah + 1.f);
        float iou = inter / (agt + aan - inter + 1e-16f);
        if (iou > best) { best = iou; bn = a; aw_b = aw; ah_b = ah; }
        if (iou > 0.6f) am |= (1 << a);
    }

    ws[D_XLO + id] = gx - 0.5f * gw;
    ws[D_XHI + id] = gx + 0.5f * gw;
    ws[D_YLO + id] = gy - 0.5f * gl;
    ws[D_YHI + id] = gy + 0.5f * gl;
    ws[D_GW + id]  = gw;
    ws[D_GL + id]  = gl;
    ws[D_Q + id]   = 0.375f * gw * gl;
    ws[D_TW + id]  = logf(gw / aw_b + 1e-16f);
    ws[D_TL + id]  = logf(gl / ah_b + 1e-16f);
    ws[D_TIM + id] = tim;
    ws[D_TRE + id] = tre;
    ws[D_GX + id]  = gx;
    ws[D_GY + id]  = gy;

    int meta = 0;
    if (valid || validp) {
        meta = gi | (gj << 8) | (bn << 16) | (am << 19)
             | (valid ? (1 << 24) : 0) | (validp ? (1 << 25) : 0)
             | ((((int)lab) & 7) << 26);
    }
    ((int*)ws)[D_META + id] = meta;
}

// o[0..6]=loss terms, o[7]=count; lab via select (no scratch)
__device__ __forceinline__ void win_terms(const float* __restrict__ xp,
                                          float tx, float ty, float twv, float tlv,
                                          float timv, float trev, int lab,
                                          float* __restrict__ o) {
    float l[14];
    #pragma unroll
    for (int c = 0; c < 14; ++c) l[c] = xp[c * HW];
    float px = 1.f / (1.f + __expf(-l[0]));
    float py = 1.f / (1.f + __expf(-l[1]));
    o[0] = (px - tx) * (px - tx);
    o[1] = (py - ty) * (py - ty);
    float dw = l[2] - twv; o[2] = dw * dw;
    float dh = l[3] - tlv; o[3] = dh * dh;
    float di = l[4] - timv, dr = l[5] - trev;
    o[4] = di * di + dr * dr;
    o[5] = sp_f(-l[6]);
    float mx = l[7];
    #pragma unroll
    for (int c = 8; c < 14; ++c) mx = fmaxf(mx, l[c]);
    float e[7], se = 0.f;
    #pragma unroll
    for (int c = 0; c < 7; ++c) { e[c] = __expf(l[7 + c] - mx); se += e[c]; }
    float se2 = 0.f, slab = 0.f;
    #pragma unroll
    for (int c = 0; c < 7; ++c) {
        float s = e[c] / se;
        se2 += __expf(s);
        if (c == lab) slab = s;
    }
    o[6] = __logf(se2) - slab;
    o[7] = 1.f;
}

// ---------- K1: zero mask + prep descriptors (round-5/11 proven) ----------
__global__ void __launch_bounds__(256) k_prep_zero(const float* __restrict__ tgt,
                                                   const float* __restrict__ anchors,
                                                   float* __restrict__ ws) {
    int gtid = blockIdx.x * 256 + threadIdx.x;
    if (gtid < NWORDS) ((unsigned int*)ws)[M_WORD + gtid] = 0u;
    if (gtid < NTGT) prep_one(gtid, tgt, anchors, ws);
}

// ---------- K2: scatter(+first-set subtract) / winner / grand-sum ----------
__global__ void __launch_bounds__(256) k_work(const float* __restrict__ x,
                                              const float* __restrict__ tgt,
                                              const float* __restrict__ anchors,
                                              float* __restrict__ ws) {
    __shared__ float redA[256], redB[256];
    int tid = threadIdx.x, bx = blockIdx.x;
    const int* meta = (const int*)ws + D_META;
    unsigned int* mask = (unsigned int*)ws + M_WORD;

    if (bx < NTGT) {
        // ---- scatter role: iou rect + overrides; subtract on first-set ----
        int id = bx;
        int b = id / NT;
        int mt = meta[id];
        float sub = 0.f, cnt = 0.f;

        if ((mt & (1 << 24)) && tid == 0) {
            int gi = mt & 255, gj = (mt >> 8) & 255;
            int bn = (mt >> 16) & 7, am = (mt >> 19) & 31;
            for (int a = 0; a < NA; ++a) {
                if (((am >> a) & 1) || a == bn) {
                    int c = ((b * NA + a) * NH + gj) * NW + gi;
                    unsigned int old = atomicOr(&mask[c >> 5], 1u << (c & 31));
                    if (!((old >> (c & 31)) & 1u)) {
                        cnt += 1.f;
                        sub += sp_f(x[(size_t)(b * CH + a * 14 + 6) * HW + gj * NW + gi]);
                    }
                }
            }
        }
        if (mt & (1 << 25)) {
            float gxv = ws[D_GX + id], gyv = ws[D_GY + id];
            float tgw = ws[D_GW + id], tgl = ws[D_GL + id];
            float txlo = ws[D_XLO + id], txhi = ws[D_XHI + id];
            float tylo = ws[D_YLO + id], tyhi = ws[D_YHI + id];
            float tq = ws[D_Q + id];
            if (tgw > 0.f && tgl > 0.f) {
                // proven reach: pass => |bx-gx| < gw/3, |by-gy| < gl/3 (+1 margin)
                float gw3 = tgw * (1.f / 3.f), gl3 = tgl * (1.f / 3.f);
                int i_lo = max(0, (int)floorf(gxv - gw3) - 1);
                int i_hi = min(NW - 1, (int)floorf(gxv + gw3) + 1);
                int j_lo = max(0, (int)floorf(gyv - gl3) - 1);
                int j_hi = min(NH - 1, (int)floorf(gyv + gl3) + 1);
                int W = i_hi - i_lo + 1, Hh = j_hi - j_lo + 1;
                int total = W * Hh * NA;
                for (int idx = tid; idx < total; idx += 256) {
                    int dx = idx % W;
                    int q2 = idx / W;
                    int j = j_lo + q2 % Hh;
                    int a = q2 / Hh;
                    int i = i_lo + dx;
                    const float* xp = x + (size_t)(b * CH + a * 14) * HW + j * NW + i;
                    float l0 = xp[0], l1 = xp[HW], l2 = xp[2 * HW], l3 = xp[3 * HW];
                    float aw = anchors[2 * a], ah = anchors[2 * a + 1];
                    float bxv = (float)i + 1.f / (1.f + __expf(-l0));
                    float byv = (float)j + 1.f / (1.f + __expf(-l1));
                    float bw = __expf(l2) * aw;
                    float bh = __expf(l3) * ah;
                    float mxv = fminf(bxv - 0.5f * bw, txlo);
                    float Mxv = fmaxf(bxv + 0.5f * bw, txhi);
                    float myv = fminf(byv - 0.5f * bh, tylo);
                    float Myv = fmaxf(byv + 0.5f * bh, tyhi);
                    float cw = bw + tgw - (Mxv - mxv);
                    float chh = bh + tgl - (Myv - myv);
                    // iou > 0.6  <=>  carea > 0.375*(area_b + area_g)
                    if (cw > 0.f && chh > 0.f && cw * chh > 0.375f * bw * bh + tq) {
                        int c = ((b * NA + a) * NH + j) * NW + i;
                        unsigned int old = atomicOr(&mask[c >> 5], 1u << (c & 31));
                        if (!((old >> (c & 31)) & 1u)) {
                            cnt += 1.f;
                            sub += sp_f(xp[6 * HW]);
                        }
                    }
                }
            }
        }
        redA[tid] = sub; redB[tid] = cnt;
        __syncthreads();
        for (int s = 128; s > 0; s >>= 1) {
            if (tid < s) { redA[tid] += redA[tid + s]; redB[tid] += redB[tid + s]; }
            __syncthreads();
        }
        if (tid == 0) { ws[S_SUB + id] = redA[0]; ws[S_CNT + id] = redB[0]; }
    } else if (bx < 2 * NTGT + 1) {
        // ---- winner role: one 8-float private slot each, no atomics -------
        int w = bx - NTGT;                 // 0..NTGT (NTGT == c* slot)
        __shared__ int flag;
        int mt = (w < NTGT) ? meta[w] : 0;
        if (tid == 0) flag = 0;
        __syncthreads();
        if (w == NTGT) {
            for (int id = tid; id < NTGT; id += 256) {
                const float* tp = tgt + (size_t)id * 7;
                float s7 = tp[0] + tp[1] + tp[2] + tp[3] + tp[4] + tp[5] + tp[6];
                if (s7 == 0.f) flag = 1;   // wrap exists (benign monotone race)
            }
        } else if (mt & (1 << 24)) {
            int b = w / NT, t = w - b * NT;
            int key = mt & 0x7FFFF;
            int t2 = t + 1 + tid;
            if (t2 < NT) {
                int m2 = meta[b * NT + t2];
                if ((m2 & (1 << 24)) && ((m2 & 0x7FFFF) == key)) flag = 1;
            }
        }
        __syncthreads();
        if (tid == 0) {
            float slot[8] = {0.f, 0.f, 0.f, 0.f, 0.f, 0.f, 0.f, 0.f};
            if (w == NTGT) {
                // np negative-index wrap cell c*: last invalid row's values
                float sub = 0.f, cnt = 0.f;
                if (flag) {
                    const float* xp = x + (size_t)((NB - 1) * CH + (NA - 1) * 14) * HW
                                      + (HW - 1);
                    float L16 = logf(1e-16f);
                    win_terms(xp, 0.f, 0.f, L16, L16, 0.f, 0.f, 0, slot);
                    int c = NCELL - 1;
                    unsigned int old = atomicOr(&mask[c >> 5], 1u << (c & 31));
                    if (!((old >> (c & 31)) & 1u)) {
                        cnt = 1.f;
                        sub = sp_f(xp[6 * HW]);
                    }
                }
                ws[S_SUB + NTGT] = sub;
                ws[S_CNT + NTGT] = cnt;
            } else if ((mt & (1 << 24)) && !flag) {   // last-t-wins
                int b = w / NT;
                int gi = mt & 255, gj = (mt >> 8) & 255;
                int bn = (mt >> 16) & 7, lab = (mt >> 26) & 7;
                const float* xp = x + (size_t)(b * CH + bn * 14) * HW + gj * NW + gi;
                win_terms(xp, ws[D_GX + w] - (float)gi, ws[D_GY + w] - (float)gj,
                          ws[D_TW + w], ws[D_TL + w],
                          ws[D_TIM + w], ws[D_TRE + w], lab, slot);
            }
            float* dst = ws + S_WIN + w * 8;
            #pragma unroll
            for (int k = 0; k < 8; ++k) dst[k] = slot[k];
        }
    } else {
        // ---- sum role: mask-free grand softplus(l6) total -----------------
        int sx = bx - (2 * NTGT + 1);
        float s = 0.f;
        for (int it = 0; it < SUM_IT; ++it) {
            int c4 = (((it * NSUMB + sx) * 256) + tid) * 4;
            if (c4 < NCELL) {
                int b = c4 / AHW;
                int within = c4 - b * AHW;
                int a = within / HW;
                int rem = within - a * HW;
                const float* p = x + (size_t)(b * CH + a * 14 + 6) * HW + rem;
                float4 v = *(const float4*)p;
                s += sp_f(v.x) + sp_f(v.y) + sp_f(v.z) + sp_f(v.w);
            }
        }
        redA[tid] = s;
        __syncthreads();
        for (int st = 128; st > 0; st >>= 1) {
            if (tid < st) redA[tid] += redA[tid + st];
            __syncthreads();
        }
        if (tid == 0) ws[S_SUM + sx] = redA[0];
    }
}

// ---------------- K3: tiny deterministic reduce + loss assembly ------------
__global__ void __launch_bounds__(256) k_reduce(const float* __restrict__ ws,
                                                float* __restrict__ out) {
    int tid = threadIdx.x;
    double acc[11];
    #pragma unroll
    for (int k = 0; k < 11; ++k) acc[k] = 0.0;
    for (int s = tid; s < NTGT + 1; s += 256) {
        const float* p = ws + S_WIN + s * 8;
        #pragma unroll
        for (int k = 0; k < 8; ++k) acc[k] += (double)p[k];
        acc[8] += (double)ws[S_SUB + s];
        acc[9] += (double)ws[S_CNT + s];
    }
    for (int s = tid; s < NSUMB; s += 256) acc[10] += (double)ws[S_SUM + s];

    __shared__ double R[11][256];
    #pragma unroll
    for (int k = 0; k < 11; ++k) R[k][tid] = acc[k];
    __syncthreads();
    for (int st = 128; st > 0; st >>= 1) {
        if (tid < st) {
            #pragma unroll
            for (int k = 0; k < 11; ++k) R[k][tid] += R[k][tid + st];
        }
        __syncthreads();
    }
    if (tid == 0) {
        double nM  = fmax(R[7][0], 1.0);
        double scf = fmax((double)NCELL - R[9][0], 1.0);
        double bce = R[10][0] - R[8][0];
        double loss =
            (R[0][0] + R[1][0] + R[2][0] + R[3][0] + R[4][0] + R[5][0]) / nM
            + bce / scf
            + (1.0 / NB) * R[6][0] / nM;
        out[0] = (float)loss;
    }
}

extern "C" void kernel_launch(void* const* d_in, const int* in_sizes, int n_in,
                              void* d_out, int out_size, void* d_ws, size_t ws_size,
                              hipStream_t stream) {
    const float* x   = (const float*)d_in[0];
    const float* tgt = (const float*)d_in[1];
    const float* anc = (const float*)d_in[2];
    float* ws  = (float*)d_ws;
    float* out = (float*)d_out;

    hipLaunchKernelGGL(k_prep_zero, dim3((NWORDS + 255) / 256), dim3(256), 0, stream,
                       tgt, anc, ws);
    hipLaunchKernelGGL(k_work, dim3(GRID2), dim3(256), 0, stream, x, tgt, anc, ws);
    hipLaunchKernelGGL(k_reduce, dim3(1), dim3(256), 0, stream, ws, out);
}